// Round 15
// baseline (311.298 us; speedup 1.0000x reference)
//
#include <hip/hip_runtime.h>
#include <stdint.h>

typedef unsigned short u16;
typedef __attribute__((ext_vector_type(4))) u16 u16x4;
typedef __attribute__((ext_vector_type(8))) u16 u16x8;
typedef __attribute__((ext_vector_type(8))) __bf16 bf16x8;
typedef __attribute__((ext_vector_type(4))) float f32x4;
typedef __attribute__((ext_vector_type(16))) float f32x16;

#define D_MODEL 2048
#define N_HEADS 16
#define HEAD_DIM 128
#define BATCH 2
#define SEQ 2048
#define M_TOT (BATCH*SEQ)          // 4096
#define N_QKV (3*D_MODEL)          // 6144

__device__ __forceinline__ u16 f2b(float f) {
  union { float f; uint32_t u; } c; c.f = f;
  uint32_t u = c.u;
  uint32_t r = (u + 0x7fffu + ((u >> 16) & 1u)) >> 16;
  return (u16)r;
}

__device__ __forceinline__ void gl_lds16(const u16* g, u16* l) {
  __builtin_amdgcn_global_load_lds(
      (const __attribute__((address_space(1))) uint32_t*)g,
      (__attribute__((address_space(3))) uint32_t*)l, 16, 0, 0);
}

template <int N> __device__ __forceinline__ void waitvm() {
  if constexpr (N == 6)      asm volatile("s_waitcnt vmcnt(6)" ::: "memory");
  else if constexpr (N == 5) asm volatile("s_waitcnt vmcnt(5)" ::: "memory");
  else                       asm volatile("s_waitcnt vmcnt(0)" ::: "memory");
}

// ---------------- fused prep kernel (cast x + Wqkv transpose ONLY) ----------------
// NOTE: Wo transpose must NOT be here -- Wot aliases the front 8 MB of Wt, so it
// can only be written AFTER gemm_qkv has consumed Wt (r14 bug: fusing it here
// clobbered the Q weights before the QKV GEMM ran).
__global__ __launch_bounds__(256) void prep_kernel(
    const float* __restrict__ x, u16* __restrict__ xb,
    const float* __restrict__ Wq, const float* __restrict__ Wk,
    const float* __restrict__ Wv, u16* __restrict__ Wt) {
  __shared__ u16 Tl[128][72];
  const int bid = blockIdx.x, tid = threadIdx.x;
  if (bid < 8192) {
    int i = (bid * 256 + tid) * 4;
    f32x4 v = *(const f32x4*)(x + i);
    u16x4 o;
    o[0] = f2b(v[0]); o[1] = f2b(v[1]); o[2] = f2b(v[2]); o[3] = f2b(v[3]);
    *(u16x4*)(xb + i) = o;
    return;
  }
  const int rel = bid - 8192;
  const int k0 = (rel & 31) * 64;
  const int hh = rel >> 5;           // 0..47 = qkv*16+h
  const int qkv = hh >> 4, h = hh & 15;
  const float* src = (qkv == 0 ? Wq : qkv == 1 ? Wk : Wv) + (size_t)h * 2048 * 128;
  for (int it = 0; it < 32; ++it) {
    int idx = it * 256 + tid;
    int k = idx >> 7, d = idx & 127;
    Tl[d][k] = f2b(src[(size_t)(k0 + k) * 128 + d]);
  }
  __syncthreads();
  for (int it = 0; it < 32; ++it) {
    int idx = it * 256 + tid;
    int d = idx >> 6, kk = idx & 63;
    Wt[(size_t)(hh * 128 + d) * 2048 + k0 + kk] = Tl[d][kk];
  }
}

// Wo [2048][2048] f32 -> Wot [2048][2048] bf16 (transposed, K-major).
// Launched AFTER gemm_qkv (Wot aliases Wt's front 8 MB).
__global__ void trans_wo_kernel(const float* __restrict__ Wo, u16* __restrict__ Wot) {
  __shared__ u16 Tl[128][72];
  const int k0 = blockIdx.x * 64;     // 32 tiles
  const int n0 = blockIdx.y * 128;    // 16 tiles
  const int tid = threadIdx.x;
  for (int it = 0; it < 32; ++it) {
    int idx = it * 256 + tid;
    int k = idx >> 7, n = idx & 127;
    Tl[n][k] = f2b(Wo[(size_t)(k0 + k) * 2048 + n0 + n]);
  }
  __syncthreads();
  for (int it = 0; it < 32; ++it) {
    int idx = it * 256 + tid;
    int d = idx >> 6, kk = idx & 63;
    Wot[(size_t)(n0 + d) * 2048 + k0 + kk] = Tl[d][kk];
  }
}

// ---------- QKV GEMM: 256x384 tile, 32x32x16 MFMA, BK=32, ring-3, counted vmcnt ----------
// r9 geometry (best measured: 107 us, 43% MfmaUtil, FETCH 57 MB).
// 512 thr = 8 waves (2M x 4N), wave tile 128x96 = 4x3 32x32 fragments.
// LDS: 3 ring slots of {A[256][32], B[384][32]} bf16 (40 KB each, 120 KB).
// Row-pair interleaved layout: granule g of row r at slot (r>>1)*8 + (x^((r>>1)&7)),
// x = ((r&1)<<2)|g; staging dests tid*16-linear (rule-21), source inverts the map.
// Tile kt reads slot kt%3, stages kt+2 (5 gl_lds/thread); vmcnt(5) per tile.
// V output written directly transposed+sigma-permuted into vtb
// ([bh][128][2048], col t -> (t&~63)|sigma(t&63)) -- transpose_v kernel deleted.
__global__ __launch_bounds__(512, 2) void gemm_qkv_kernel(
    const u16* __restrict__ A, const u16* __restrict__ B,
    u16* __restrict__ qo, u16* __restrict__ ko, u16* __restrict__ vo,
    const float* __restrict__ bq, const float* __restrict__ bk, const float* __restrict__ bv) {
  __shared__ u16 LS[3][20480];   // A: [0,8192) u16, B: [8192,20480)
  const int bid0 = blockIdx.x;
  const int gid = (bid0 & 7) * 32 + (bid0 >> 3);   // XCD-chunked (256 blocks)
  const int G = gid >> 4, l = gid & 15;            // 16 groups of 4mt x 4nt
  const int m0 = ((G & 3) * 4 + (l & 3)) * 256;
  const int n0 = ((G >> 2) * 4 + (l >> 2)) * 384;

  const int tid = threadIdx.x, lane = tid & 63, w = tid >> 6;
  const int wm = (w >> 2) * 128, wn = (w & 3) * 96;
  const int l31 = lane & 31, g2 = lane >> 5;

  // staging source: chunk ci holds (r = 2*(ci>>3)+(x>>2), g = x&3), x = (ci&7)^((ci>>3)&7)
  int aoff[2], boff[3];
#pragma unroll
  for (int l2 = 0; l2 < 2; ++l2) {
    int ci = l2 * 512 + tid, t = ci >> 3, x = (ci & 7) ^ (t & 7);
    aoff[l2] = (m0 + 2 * t + (x >> 2)) * 2048 + (x & 3) * 8;
  }
#pragma unroll
  for (int l2 = 0; l2 < 3; ++l2) {
    int ci = l2 * 512 + tid, t = ci >> 3, x = (ci & 7) ^ (t & 7);
    boff[l2] = (n0 + 2 * t + (x >> 2)) * 2048 + (x & 3) * 8;
  }
  const int adl = tid * 8;
  const int bdl = 8192 + tid * 8;

  f32x16 acc[4][3];
#pragma unroll
  for (int ai = 0; ai < 4; ++ai)
#pragma unroll
    for (int bj = 0; bj < 3; ++bj)
#pragma unroll
      for (int e = 0; e < 16; ++e) acc[ai][bj][e] = 0.f;

  // prologue: stage tiles 0,1 into slots 0,1
#pragma unroll
  for (int t = 0; t < 2; ++t) {
#pragma unroll
    for (int l2 = 0; l2 < 2; ++l2) gl_lds16(A + aoff[l2] + t * 32, LS[t] + adl + l2 * 4096);
#pragma unroll
    for (int l2 = 0; l2 < 3; ++l2) gl_lds16(B + boff[l2] + t * 32, LS[t] + bdl + l2 * 4096);
  }
  waitvm<5>();
  __builtin_amdgcn_s_barrier();

  int s = 0;
  for (int kt = 0; kt < 64; ++kt) {
    if (kt < 62) {
      const int s2 = (s == 0) ? 2 : s - 1;
      const int k2 = (kt + 2) * 32;
#pragma unroll
      for (int l2 = 0; l2 < 2; ++l2) gl_lds16(A + aoff[l2] + k2, LS[s2] + adl + l2 * 4096);
#pragma unroll
      for (int l2 = 0; l2 < 3; ++l2) gl_lds16(B + boff[l2] + k2, LS[s2] + bdl + l2 * 4096);
    }
    const char* base = (const char*)LS[s];
#pragma unroll
    for (int kk = 0; kk < 2; ++kk) {
      bf16x8 af[4];
#pragma unroll
      for (int ai = 0; ai < 4; ++ai) {
        int r = wm + ai * 32 + l31;
        int x = ((r & 1) << 2) | (2 * kk + g2);
        af[ai] = *(const bf16x8*)(base + (r >> 1) * 128 + 16 * (x ^ ((r >> 1) & 7)));
      }
      __builtin_amdgcn_s_setprio(1);
#pragma unroll
      for (int bj = 0; bj < 3; ++bj) {
        int rb = wn + bj * 32 + l31;
        int xb2 = ((rb & 1) << 2) | (2 * kk + g2);
        bf16x8 bfr = *(const bf16x8*)(base + 16384 + (rb >> 1) * 128 + 16 * (xb2 ^ ((rb >> 1) & 7)));
#pragma unroll
        for (int ai = 0; ai < 4; ++ai)
          acc[ai][bj] = __builtin_amdgcn_mfma_f32_32x32x16_bf16(af[ai], bfr, acc[ai][bj], 0, 0, 0);
      }
      __builtin_amdgcn_s_setprio(0);
    }
    if (kt < 62)       waitvm<5>();
    else if (kt == 62) waitvm<0>();
    __builtin_amdgcn_s_barrier();
    s = (s == 2) ? 0 : s + 1;
  }

  // epilogue: C/D 32x32 layout col=lane&31, row=(reg&3)+8*(reg>>2)+4*(lane>>5)
  const float qscale = 0.08838834764831845f * 1.4426950408889634f;  // 1/sqrt(128)*log2e
#pragma unroll
  for (int bj = 0; bj < 3; ++bj) {
    const int n = n0 + wn + bj * 32 + l31;
    const int qkv = n >> 11, hh = (n >> 7) & 15, d = n & 127;
    const float* bias = (qkv == 0) ? bq : (qkv == 1) ? bk : bv;
    u16* dst = (qkv == 0) ? qo : ko;
    const float bv_ = bias[n & 2047];
#pragma unroll
    for (int ai = 0; ai < 4; ++ai)
#pragma unroll
      for (int e = 0; e < 16; ++e) {
        int row = (e & 3) + 8 * (e >> 2) + 4 * g2;
        int gm = m0 + wm + ai * 32 + row;
        float val = acc[ai][bj][e] + bv_;
        if (qkv == 0) val *= qscale;
        int b = gm >> 11, t = gm & 2047;
        if (qkv == 2) {
          int tt = (t & ~63) | ((t & 15) * 4 + ((t >> 4) & 3));  // sigma within 64-tile
          vo[((size_t)(b * 16 + hh)) * 262144 + (size_t)d * 2048 + tt] = f2b(val);
        } else {
          dst[((size_t)(b * 16 + hh) * 2048 + t) * 128 + d] = f2b(val);
        }
      }
  }
}

// ---------- Output GEMM: 256x128 tile, 16x16x32 MFMA, BK=64, ring-3, counted vmcnt ----------
// 512 thr = 8 waves (4M x 2N), wave 64x64 = 4x4 16x16 frags (acc 64 f32/lane).
// LDS: 3 ring slots of {A[256][64], B[128][64]} bf16 (48 KB each, 144 KB).
// Staging dests tid*8-linear (rule-21 safe); source pre-swizzled gj ^ (row&7).
// Tile kt reads slot kt%3, stages kt+2 (6 loads/thread); vmcnt(6) per tile.
__global__ __launch_bounds__(512, 2) void gemm_out_kernel(
    const u16* __restrict__ A, const u16* __restrict__ B,
    float* __restrict__ outf, const float* __restrict__ bo) {
  __shared__ u16 LS[3][24576];   // A: [0,16384) u16, B: [16384,24576)
  const int bid0 = blockIdx.x;
  const int gid = (bid0 & 7) * 32 + (bid0 >> 3);   // 256 blocks
  const int G = gid >> 4, l = gid & 15;
  const int m0 = ((G & 3) * 4 + (l & 3)) * 256;
  const int n0 = ((G >> 2) * 4 + (l >> 2)) * 128;

  const int tid = threadIdx.x, lane = tid & 63, w = tid >> 6;
  const int wm = (w >> 1) * 64, wn = (w & 1) * 64;
  const int lr = lane & 15, g = lane >> 4;
  const int kx = (lr & 7) << 4;

  int aoff[4], boff[2];
#pragma unroll
  for (int l2 = 0; l2 < 4; ++l2) {
    int ci = l2 * 512 + tid, r = ci >> 3, gj = ci & 7;
    aoff[l2] = (m0 + r) * 2048 + (gj ^ (r & 7)) * 8;
  }
#pragma unroll
  for (int l2 = 0; l2 < 2; ++l2) {
    int ci = l2 * 512 + tid, r = ci >> 3, gj = ci & 7;
    boff[l2] = (n0 + r) * 2048 + (gj ^ (r & 7)) * 8;
  }
  const int adl = tid * 8;
  const int bdl = 16384 + tid * 8;

  f32x4 acc[4][4];
  const f32x4 zero = {0.f, 0.f, 0.f, 0.f};
#pragma unroll
  for (int ai = 0; ai < 4; ++ai)
#pragma unroll
    for (int bj = 0; bj < 4; ++bj) acc[ai][bj] = zero;

#pragma unroll
  for (int t = 0; t < 2; ++t) {
#pragma unroll
    for (int l2 = 0; l2 < 4; ++l2) gl_lds16(A + aoff[l2] + t * 64, LS[t] + adl + l2 * 4096);
#pragma unroll
    for (int l2 = 0; l2 < 2; ++l2) gl_lds16(B + boff[l2] + t * 64, LS[t] + bdl + l2 * 4096);
  }
  waitvm<6>();
  __builtin_amdgcn_s_barrier();

  int s = 0;
  for (int kt = 0; kt < 32; ++kt) {
    if (kt < 30) {
      const int s2 = (s == 0) ? 2 : s - 1;
      const int k2 = (kt + 2) * 64;
#pragma unroll
      for (int l2 = 0; l2 < 4; ++l2) gl_lds16(A + aoff[l2] + k2, LS[s2] + adl + l2 * 4096);
#pragma unroll
      for (int l2 = 0; l2 < 2; ++l2) gl_lds16(B + boff[l2] + k2, LS[s2] + bdl + l2 * 4096);
    }
    const char* base = (const char*)LS[s];
#pragma unroll
    for (int h = 0; h < 2; ++h) {
      bf16x8 af[4];
#pragma unroll
      for (int ai = 0; ai < 4; ++ai) {
        int r = wm + ai * 16 + lr;
        af[ai] = *(const bf16x8*)(base + r * 128 + ((h * 64 + 16 * g) ^ kx));
      }
      __builtin_amdgcn_s_setprio(1);
#pragma unroll
      for (int bj = 0; bj < 4; ++bj) {
        int rb = wn + bj * 16 + lr;
        bf16x8 bfr = *(const bf16x8*)(base + 32768 + rb * 128 + ((h * 64 + 16 * g) ^ kx));
#pragma unroll
        for (int ai = 0; ai < 4; ++ai)
          acc[ai][bj] = __builtin_amdgcn_mfma_f32_16x16x32_bf16(af[ai], bfr, acc[ai][bj], 0, 0, 0);
      }
      __builtin_amdgcn_s_setprio(0);
    }
    if (kt < 30)       waitvm<6>();
    else if (kt == 30) waitvm<0>();
    __builtin_amdgcn_s_barrier();
    s = (s == 2) ? 0 : s + 1;
  }

  const int rbase = g * 4;
#pragma unroll
  for (int bj = 0; bj < 4; ++bj) {
    const int gn = n0 + wn + bj * 16 + lr;
    const float bv_ = bo[gn];
#pragma unroll
    for (int ai = 0; ai < 4; ++ai)
#pragma unroll
      for (int r = 0; r < 4; ++r) {
        int gm = m0 + wm + ai * 16 + rbase + r;
        outf[(size_t)gm * 2048 + gn] = acc[ai][bj][r] + bv_;
      }
  }
}

// ---------------- flash attention (causal) ----------------
// 512 blocks of 256 threads; bid -> bh = bid&31 (XCD-grouped), qt = 15-(bid>>5).
// 4 waves x 32 q-rows; KV tile 64, double-buffered, gl_lds staging pre-swizzled.
// P-pack via v_cvt_pk_bf16_f32; per-lane row-sum partials; defer-max; sigma'd V^T.
__global__ __launch_bounds__(256) void attn_kernel(
    const u16* __restrict__ qg, const u16* __restrict__ kg,
    const u16* __restrict__ vtg, u16* __restrict__ y) {
  __shared__ u16 Kb[2][64 * 128];
  __shared__ u16 Vb[2][128 * 64];
  __shared__ u16 Pl[4][32 * 64];
  const int tid = threadIdx.x, lane = tid & 63, w = tid >> 6;
  const int bid = blockIdx.x;
  const int bh = bid & 31, qt = 15 - (bid >> 5);
  const int b = bh >> 4, h = bh & 15;
  const int lr = lane & 15, lk = (lane >> 4) * 8;
  const u16* Qp = qg + (size_t)bh * (2048 * 128);
  const u16* Kp = kg + (size_t)bh * (2048 * 128);
  const u16* Vp = vtg + (size_t)bh * (128 * 2048);

  int koff[4], voff[4], dstc[4];
#pragma unroll
  for (int c = 0; c < 4; ++c) {
    int ci = c * 256 + tid;
    dstc[c] = ci * 8;
    int kr = ci >> 4, kj = ci & 15;
    koff[c] = kr * 128 + (kj ^ (kr & 7)) * 8;
    int vd = ci >> 3, vj = ci & 7;
    voff[c] = vd * 2048 + (vj ^ (vd & 7)) * 8;
  }
  const int kxor = (lr & 7) << 4;
  const int rbase = (lane >> 4) * 4;
  const f32x4 zero = {0.f, 0.f, 0.f, 0.f};

  const int q0 = qt * 128;
  const int qw = q0 + w * 32;
  const int nt = 2 * qt + 2;

  bf16x8 qf[2][4];
#pragma unroll
  for (int s = 0; s < 2; ++s)
#pragma unroll
    for (int i = 0; i < 4; ++i)
      qf[s][i] = *(const bf16x8*)(Qp + (size_t)(qw + s * 16 + lr) * 128 + i * 32 + lk);

  f32x4 o[2][8];
#pragma unroll
  for (int s = 0; s < 2; ++s)
#pragma unroll
    for (int f = 0; f < 8; ++f) o[s][f] = zero;
  float mrow[2][4], lrow[2][4];
#pragma unroll
  for (int s = 0; s < 2; ++s)
#pragma unroll
    for (int r = 0; r < 4; ++r) { mrow[s][r] = -1e30f; lrow[s][r] = 0.f; }

#pragma unroll
  for (int c = 0; c < 4; ++c) gl_lds16(Kp + koff[c], Kb[0] + dstc[c]);
#pragma unroll
  for (int c = 0; c < 4; ++c) gl_lds16(Vp + voff[c], Vb[0] + dstc[c]);
  __syncthreads();

  int cur = 0;
  for (int t = 0; t < nt; ++t) {
    const int s0 = t * 64;
    if (t + 1 < nt) {
      const size_t skn = (size_t)(s0 + 64) * 128;
#pragma unroll
      for (int c = 0; c < 4; ++c) gl_lds16(Kp + skn + koff[c], Kb[cur ^ 1] + dstc[c]);
#pragma unroll
      for (int c = 0; c < 4; ++c) gl_lds16(Vp + (s0 + 64) + voff[c], Vb[cur ^ 1] + dstc[c]);
    }
    if (s0 <= qw + 31) {
      const char* Kc = (const char*)Kb[cur];
      f32x4 sf[2][4];
      __builtin_amdgcn_s_setprio(1);
#pragma unroll
      for (int sj = 0; sj < 4; ++sj) {
        f32x4 a0 = zero, a1 = zero;
#pragma unroll
        for (int i = 0; i < 4; ++i) {
          bf16x8 kf = *(const bf16x8*)(Kc + ((((sj * 16 + lr) * 256) + (i * 32 + lk) * 2) ^ kxor));
          a0 = __builtin_amdgcn_mfma_f32_16x16x32_bf16(qf[0][i], kf, a0, 0, 0, 0);
          a1 = __builtin_amdgcn_mfma_f32_16x16x32_bf16(qf[1][i], kf, a1, 0, 0, 0);
        }
        sf[0][sj] = a0; sf[1][sj] = a1;
      }
      __builtin_amdgcn_s_setprio(0);

      char* Pc = (char*)Pl[w];
      const bool diag = (s0 + 63 > qw);
      float pmax[2][4];
      bool need = false;
#pragma unroll
      for (int s = 0; s < 2; ++s)
#pragma unroll
        for (int r = 0; r < 4; ++r) {
          if (diag) {
            const int rq = qw + s * 16 + rbase + r;
#pragma unroll
            for (int sj = 0; sj < 4; ++sj)
              if (s0 + sj * 16 + lr > rq) sf[s][sj][r] = -1e30f;
          }
          float pm = fmaxf(fmaxf(sf[s][0][r], sf[s][1][r]),
                           fmaxf(sf[s][2][r], sf[s][3][r]));
          pmax[s][r] = pm;
          need |= (pm > mrow[s][r] + 8.f);
        }
      if (__any(need)) {
#pragma unroll
        for (int s = 0; s < 2; ++s)
#pragma unroll
          for (int r = 0; r < 4; ++r) {
            float pm = pmax[s][r];
            pm = fmaxf(pm, __shfl_xor(pm, 1));
            pm = fmaxf(pm, __shfl_xor(pm, 2));
            pm = fmaxf(pm, __shfl_xor(pm, 4));
            pm = fmaxf(pm, __shfl_xor(pm, 8));
            float mnew = fmaxf(mrow[s][r], pm);
            float sfac = __builtin_amdgcn_exp2f(mrow[s][r] - mnew);
            mrow[s][r] = mnew;
            lrow[s][r] *= sfac;
#pragma unroll
            for (int f = 0; f < 8; ++f) o[s][f][r] *= sfac;
          }
      }
#pragma unroll
      for (int s = 0; s < 2; ++s)
#pragma unroll
        for (int r = 0; r < 4; ++r) {
          const int prow = s * 16 + rbase + r;
          float p0 = __builtin_amdgcn_exp2f(sf[s][0][r] - mrow[s][r]);
          float p1 = __builtin_amdgcn_exp2f(sf[s][1][r] - mrow[s][r]);
          float p2 = __builtin_amdgcn_exp2f(sf[s][2][r] - mrow[s][r]);
          float p3 = __builtin_amdgcn_exp2f(sf[s][3][r] - mrow[s][r]);
          lrow[s][r] += (p0 + p1) + (p2 + p3);
          uint32_t lo, hi;
          asm("v_cvt_pk_bf16_f32 %0, %1, %2" : "=v"(lo) : "v"(p0), "v"(p1));
          asm("v_cvt_pk_bf16_f32 %0, %1, %2" : "=v"(hi) : "v"(p2), "v"(p3));
          uint32_t* pp = (uint32_t*)(Pc + ((prow * 128 + lr * 8) ^ ((prow & 7) << 4)));
          pp[0] = lo; pp[1] = hi;
        }

      const char* Vc = (const char*)Vb[cur];
      __builtin_amdgcn_s_setprio(1);
#pragma unroll
      for (int st = 0; st < 2; ++st) {
        bf16x8 pf0 = *(const bf16x8*)(Pc + (((lr * 128) + (st * 32 + lk) * 2) ^ kxor));
        bf16x8 pf1 = *(const bf16x8*)(Pc + ((((16 + lr) * 128) + (st * 32 + lk) * 2) ^ kxor));
#pragma unroll
        for (int f = 0; f < 8; ++f) {
          bf16x8 vf = *(const bf16x8*)(Vc + ((((f * 16 + lr) * 128) + (st * 32 + lk) * 2) ^ kxor));
          o[0][f] = __builtin_amdgcn_mfma_f32_16x16x32_bf16(pf0, vf, o[0][f], 0, 0, 0);
          o[1][f] = __builtin_amdgcn_mfma_f32_16x16x32_bf16(pf1, vf, o[1][f], 0, 0, 0);
        }
      }
      __builtin_amdgcn_s_setprio(0);
    }
    __syncthreads();
    cur ^= 1;
  }

#pragma unroll
  for (int s = 0; s < 2; ++s)
#pragma unroll
    for (int r = 0; r < 4; ++r) {
      float l = lrow[s][r];
      l += __shfl_xor(l, 1);
      l += __shfl_xor(l, 2);
      l += __shfl_xor(l, 4);
      l += __shfl_xor(l, 8);
      const float rinv = __builtin_amdgcn_rcpf(l);
      const int row = qw + s * 16 + rbase + r;
#pragma unroll
      for (int f = 0; f < 8; ++f)
        y[((size_t)b * 2048 + row) * 2048 + h * 128 + f * 16 + lr] =
            f2b(o[s][f][r] * rinv);
    }
}

// ---------------- launch ----------------

extern "C" void kernel_launch(void* const* d_in, const int* in_sizes, int n_in,
                              void* d_out, int out_size, void* d_ws, size_t ws_size,
                              hipStream_t stream) {
  const float* x  = (const float*)d_in[0];
  const float* Wq = (const float*)d_in[1];
  const float* bq = (const float*)d_in[2];
  const float* Wk = (const float*)d_in[3];
  const float* bk = (const float*)d_in[4];
  const float* Wv = (const float*)d_in[5];
  const float* bv = (const float*)d_in[6];
  const float* Wo = (const float*)d_in[7];
  const float* bo = (const float*)d_in[8];
  float* out = (float*)d_out;
  char* ws = (char*)d_ws;

  u16* xb  = (u16*)(ws + 0);          // 16 MB; reused as yb after QKV GEMM
  u16* Wt  = (u16*)(ws + 16777216);   // 24 MB; front 8 MB reused as Wot AFTER gemm_qkv
  u16* qb  = (u16*)(ws + 41943040);   // 16 MB
  u16* kb  = (u16*)(ws + 58720256);   // 16 MB
  u16* vtb = (u16*)(ws + 75497472);   // 16 MB: V^T [B*H][128][2048], sigma'd (total 88 MB)
  u16* Wot = Wt;                      // [2048][2048] bf16 = 8 MB
  u16* yb  = xb;

  prep_kernel<<<9728, 256, 0, stream>>>(x, xb, Wq, Wk, Wv, Wt);
  gemm_qkv_kernel<<<256, 512, 0, stream>>>(xb, Wt, qb, kb, vtb, bq, bk, bv);
  trans_wo_kernel<<<dim3(32, 16), 256, 0, stream>>>(Wo, Wot);
  attn_kernel<<<512, 256, 0, stream>>>(qb, kb, vtb, yb);
  gemm_out_kernel<<<256, 512, 0, stream>>>(yb, Wot, out, bo);
}

// Round 16
// 274.222 us; speedup vs baseline: 1.1352x; 1.1352x over previous
//
#include <hip/hip_runtime.h>
#include <stdint.h>

typedef unsigned short u16;
typedef __attribute__((ext_vector_type(4))) u16 u16x4;
typedef __attribute__((ext_vector_type(8))) u16 u16x8;
typedef __attribute__((ext_vector_type(8))) __bf16 bf16x8;
typedef __attribute__((ext_vector_type(4))) float f32x4;
typedef __attribute__((ext_vector_type(16))) float f32x16;

#define D_MODEL 2048
#define N_HEADS 16
#define HEAD_DIM 128
#define BATCH 2
#define SEQ 2048
#define M_TOT (BATCH*SEQ)          // 4096
#define N_QKV (3*D_MODEL)          // 6144

__device__ __forceinline__ u16 f2b(float f) {
  union { float f; uint32_t u; } c; c.f = f;
  uint32_t u = c.u;
  uint32_t r = (u + 0x7fffu + ((u >> 16) & 1u)) >> 16;
  return (u16)r;
}

__device__ __forceinline__ void gl_lds16(const u16* g, u16* l) {
  __builtin_amdgcn_global_load_lds(
      (const __attribute__((address_space(1))) uint32_t*)g,
      (__attribute__((address_space(3))) uint32_t*)l, 16, 0, 0);
}

template <int N> __device__ __forceinline__ void waitvm() {
  if constexpr (N == 6)      asm volatile("s_waitcnt vmcnt(6)" ::: "memory");
  else if constexpr (N == 5) asm volatile("s_waitcnt vmcnt(5)" ::: "memory");
  else                       asm volatile("s_waitcnt vmcnt(0)" ::: "memory");
}

// ---------------- fused prep kernel (cast x + Wqkv transpose) ----------------
// Wo transpose NOT here: Wot aliases Wt's front 8 MB, must run after gemm_qkv.
__global__ __launch_bounds__(256) void prep_kernel(
    const float* __restrict__ x, u16* __restrict__ xb,
    const float* __restrict__ Wq, const float* __restrict__ Wk,
    const float* __restrict__ Wv, u16* __restrict__ Wt) {
  __shared__ u16 Tl[128][72];
  const int bid = blockIdx.x, tid = threadIdx.x;
  if (bid < 8192) {
    int i = (bid * 256 + tid) * 4;
    f32x4 v = *(const f32x4*)(x + i);
    u16x4 o;
    o[0] = f2b(v[0]); o[1] = f2b(v[1]); o[2] = f2b(v[2]); o[3] = f2b(v[3]);
    *(u16x4*)(xb + i) = o;
    return;
  }
  const int rel = bid - 8192;
  const int k0 = (rel & 31) * 64;
  const int hh = rel >> 5;           // 0..47 = qkv*16+h
  const int qkv = hh >> 4, h = hh & 15;
  const float* src = (qkv == 0 ? Wq : qkv == 1 ? Wk : Wv) + (size_t)h * 2048 * 128;
  for (int it = 0; it < 32; ++it) {
    int idx = it * 256 + tid;
    int k = idx >> 7, d = idx & 127;
    Tl[d][k] = f2b(src[(size_t)(k0 + k) * 128 + d]);
  }
  __syncthreads();
  for (int it = 0; it < 32; ++it) {
    int idx = it * 256 + tid;
    int d = idx >> 6, kk = idx & 63;
    Wt[(size_t)(hh * 128 + d) * 2048 + k0 + kk] = Tl[d][kk];
  }
}

// Wo [2048][2048] f32 -> Wot [2048][2048] bf16 (transposed, K-major).
// Launched AFTER gemm_qkv (Wot aliases Wt's front 8 MB).
__global__ void trans_wo_kernel(const float* __restrict__ Wo, u16* __restrict__ Wot) {
  __shared__ u16 Tl[128][72];
  const int k0 = blockIdx.x * 64;     // 32 tiles
  const int n0 = blockIdx.y * 128;    // 16 tiles
  const int tid = threadIdx.x;
  for (int it = 0; it < 32; ++it) {
    int idx = it * 256 + tid;
    int k = idx >> 7, n = idx & 127;
    Tl[n][k] = f2b(Wo[(size_t)(k0 + k) * 2048 + n0 + n]);
  }
  __syncthreads();
  for (int it = 0; it < 32; ++it) {
    int idx = it * 256 + tid;
    int d = idx >> 6, kk = idx & 63;
    Wot[(size_t)(n0 + d) * 2048 + k0 + kk] = Tl[d][kk];
  }
}

// vb [B,H,T,128] bf16 -> vt [B,H,128,T] bf16 with sigma-permuted columns within
// each 64-tile: sigma(t) = (t&15)*4 + (t>>4). Matches attn's packed-P k-space.
__global__ void transpose_v_kernel(const u16* __restrict__ vb, u16* __restrict__ vt) {
  __shared__ u16 Tl[128 * 65];
  const int bh = blockIdx.y;
  const int t0 = blockIdx.x * 64;
  const int tid = threadIdx.x;
  const u16* src = vb + (size_t)bh * 2048 * 128;
  u16* dstp = vt + (size_t)bh * 128 * 2048;
#pragma unroll
  for (int c = 0; c < 4; ++c) {
    int ci = c * 256 + tid;
    int tr = ci >> 4, d0 = (ci & 15) * 8;
    u16x8 v = *(const u16x8*)(src + (size_t)(t0 + tr) * 128 + d0);
#pragma unroll
    for (int e = 0; e < 8; ++e) Tl[(d0 + e) * 65 + tr] = v[e];
  }
  __syncthreads();
#pragma unroll
  for (int it = 0; it < 32; ++it) {
    int idx = it * 256 + tid;
    int d = idx >> 6, tt = idx & 63;
    dstp[(size_t)d * 2048 + t0 + ((tt & 15) * 4 + (tt >> 4))] = Tl[d * 65 + tt];
  }
}

// ---------- QKV GEMM: 256x384 tile, 32x32x16 MFMA, BK=32, ring-3, counted vmcnt ----------
// r9/r10 geometry (best measured: 107 us, 43% MfmaUtil, FETCH 57 MB).
// 512 thr = 8 waves (2M x 4N), wave tile 128x96 = 4x3 32x32 fragments.
// LDS: 3 ring slots of {A[256][32], B[384][32]} bf16 (40 KB each, 120 KB).
// Row-pair interleaved layout: granule g of row r at slot (r>>1)*8 + (x^((r>>1)&7)),
// x = ((r&1)<<2)|g; staging dests tid*16-linear (rule-21), source inverts the map.
// Tile kt reads slot kt%3, stages kt+2 (5 gl_lds/thread); vmcnt(5) per tile.
// Epilogue: coalesced [B,H,T,D] stores for all of Q/K/V (r15 lesson: V^T scatter
// in the epilogue costs 48 us in partial-line RMW; the 8-us transpose kernel wins).
__global__ __launch_bounds__(512, 2) void gemm_qkv_kernel(
    const u16* __restrict__ A, const u16* __restrict__ B,
    u16* __restrict__ qo, u16* __restrict__ ko, u16* __restrict__ vo,
    const float* __restrict__ bq, const float* __restrict__ bk, const float* __restrict__ bv) {
  __shared__ u16 LS[3][20480];   // A: [0,8192) u16, B: [8192,20480)
  const int bid0 = blockIdx.x;
  const int gid = (bid0 & 7) * 32 + (bid0 >> 3);   // XCD-chunked (256 blocks)
  const int G = gid >> 4, l = gid & 15;            // 16 groups of 4mt x 4nt
  const int m0 = ((G & 3) * 4 + (l & 3)) * 256;
  const int n0 = ((G >> 2) * 4 + (l >> 2)) * 384;

  const int tid = threadIdx.x, lane = tid & 63, w = tid >> 6;
  const int wm = (w >> 2) * 128, wn = (w & 3) * 96;
  const int l31 = lane & 31, g2 = lane >> 5;

  // staging source: chunk ci holds (r = 2*(ci>>3)+(x>>2), g = x&3), x = (ci&7)^((ci>>3)&7)
  int aoff[2], boff[3];
#pragma unroll
  for (int l2 = 0; l2 < 2; ++l2) {
    int ci = l2 * 512 + tid, t = ci >> 3, x = (ci & 7) ^ (t & 7);
    aoff[l2] = (m0 + 2 * t + (x >> 2)) * 2048 + (x & 3) * 8;
  }
#pragma unroll
  for (int l2 = 0; l2 < 3; ++l2) {
    int ci = l2 * 512 + tid, t = ci >> 3, x = (ci & 7) ^ (t & 7);
    boff[l2] = (n0 + 2 * t + (x >> 2)) * 2048 + (x & 3) * 8;
  }
  const int adl = tid * 8;
  const int bdl = 8192 + tid * 8;

  f32x16 acc[4][3];
#pragma unroll
  for (int ai = 0; ai < 4; ++ai)
#pragma unroll
    for (int bj = 0; bj < 3; ++bj)
#pragma unroll
      for (int e = 0; e < 16; ++e) acc[ai][bj][e] = 0.f;

  // prologue: stage tiles 0,1 into slots 0,1
#pragma unroll
  for (int t = 0; t < 2; ++t) {
#pragma unroll
    for (int l2 = 0; l2 < 2; ++l2) gl_lds16(A + aoff[l2] + t * 32, LS[t] + adl + l2 * 4096);
#pragma unroll
    for (int l2 = 0; l2 < 3; ++l2) gl_lds16(B + boff[l2] + t * 32, LS[t] + bdl + l2 * 4096);
  }
  waitvm<5>();
  __builtin_amdgcn_s_barrier();

  int s = 0;
  for (int kt = 0; kt < 64; ++kt) {
    if (kt < 62) {
      const int s2 = (s == 0) ? 2 : s - 1;
      const int k2 = (kt + 2) * 32;
#pragma unroll
      for (int l2 = 0; l2 < 2; ++l2) gl_lds16(A + aoff[l2] + k2, LS[s2] + adl + l2 * 4096);
#pragma unroll
      for (int l2 = 0; l2 < 3; ++l2) gl_lds16(B + boff[l2] + k2, LS[s2] + bdl + l2 * 4096);
    }
    const char* base = (const char*)LS[s];
#pragma unroll
    for (int kk = 0; kk < 2; ++kk) {
      bf16x8 af[4];
#pragma unroll
      for (int ai = 0; ai < 4; ++ai) {
        int r = wm + ai * 32 + l31;
        int x = ((r & 1) << 2) | (2 * kk + g2);
        af[ai] = *(const bf16x8*)(base + (r >> 1) * 128 + 16 * (x ^ ((r >> 1) & 7)));
      }
      __builtin_amdgcn_s_setprio(1);
#pragma unroll
      for (int bj = 0; bj < 3; ++bj) {
        int rb = wn + bj * 32 + l31;
        int xb2 = ((rb & 1) << 2) | (2 * kk + g2);
        bf16x8 bfr = *(const bf16x8*)(base + 16384 + (rb >> 1) * 128 + 16 * (xb2 ^ ((rb >> 1) & 7)));
#pragma unroll
        for (int ai = 0; ai < 4; ++ai)
          acc[ai][bj] = __builtin_amdgcn_mfma_f32_32x32x16_bf16(af[ai], bfr, acc[ai][bj], 0, 0, 0);
      }
      __builtin_amdgcn_s_setprio(0);
    }
    if (kt < 62)       waitvm<5>();
    else if (kt == 62) waitvm<0>();
    __builtin_amdgcn_s_barrier();
    s = (s == 2) ? 0 : s + 1;
  }

  // epilogue: C/D 32x32 layout col=lane&31, row=(reg&3)+8*(reg>>2)+4*(lane>>5)
  const float qscale = 0.08838834764831845f * 1.4426950408889634f;  // 1/sqrt(128)*log2e
#pragma unroll
  for (int bj = 0; bj < 3; ++bj) {
    const int n = n0 + wn + bj * 32 + l31;
    const int qkv = n >> 11, hh = (n >> 7) & 15, d = n & 127;
    const float* bias = (qkv == 0) ? bq : (qkv == 1) ? bk : bv;
    u16* dst = (qkv == 0) ? qo : (qkv == 1) ? ko : vo;
    const float bv_ = bias[n & 2047];
#pragma unroll
    for (int ai = 0; ai < 4; ++ai)
#pragma unroll
      for (int e = 0; e < 16; ++e) {
        int row = (e & 3) + 8 * (e >> 2) + 4 * g2;
        int gm = m0 + wm + ai * 32 + row;
        float val = acc[ai][bj][e] + bv_;
        if (qkv == 0) val *= qscale;
        int b = gm >> 11, t = gm & 2047;
        dst[((size_t)(b * 16 + hh) * 2048 + t) * 128 + d] = f2b(val);
      }
  }
}

// ---------- Output GEMM: 256x128 tile, 16x16x32 MFMA, BK=64, ring-3, counted vmcnt ----------
// 512 thr = 8 waves (4M x 2N), wave 64x64 = 4x4 16x16 frags (acc 64 f32/lane).
// LDS: 3 ring slots of {A[256][64], B[128][64]} bf16 (48 KB each, 144 KB).
// Staging dests tid*8-linear (rule-21 safe); source pre-swizzled gj ^ (row&7).
// Tile kt reads slot kt%3, stages kt+2 (6 loads/thread); vmcnt(6) per tile.
__global__ __launch_bounds__(512, 2) void gemm_out_kernel(
    const u16* __restrict__ A, const u16* __restrict__ B,
    float* __restrict__ outf, const float* __restrict__ bo) {
  __shared__ u16 LS[3][24576];   // A: [0,16384) u16, B: [16384,24576)
  const int bid0 = blockIdx.x;
  const int gid = (bid0 & 7) * 32 + (bid0 >> 3);   // 256 blocks
  const int G = gid >> 4, l = gid & 15;
  const int m0 = ((G & 3) * 4 + (l & 3)) * 256;
  const int n0 = ((G >> 2) * 4 + (l >> 2)) * 128;

  const int tid = threadIdx.x, lane = tid & 63, w = tid >> 6;
  const int wm = (w >> 1) * 64, wn = (w & 1) * 64;
  const int lr = lane & 15, g = lane >> 4;
  const int kx = (lr & 7) << 4;

  int aoff[4], boff[2];
#pragma unroll
  for (int l2 = 0; l2 < 4; ++l2) {
    int ci = l2 * 512 + tid, r = ci >> 3, gj = ci & 7;
    aoff[l2] = (m0 + r) * 2048 + (gj ^ (r & 7)) * 8;
  }
#pragma unroll
  for (int l2 = 0; l2 < 2; ++l2) {
    int ci = l2 * 512 + tid, r = ci >> 3, gj = ci & 7;
    boff[l2] = (n0 + r) * 2048 + (gj ^ (r & 7)) * 8;
  }
  const int adl = tid * 8;
  const int bdl = 16384 + tid * 8;

  f32x4 acc[4][4];
  const f32x4 zero = {0.f, 0.f, 0.f, 0.f};
#pragma unroll
  for (int ai = 0; ai < 4; ++ai)
#pragma unroll
    for (int bj = 0; bj < 4; ++bj) acc[ai][bj] = zero;

#pragma unroll
  for (int t = 0; t < 2; ++t) {
#pragma unroll
    for (int l2 = 0; l2 < 4; ++l2) gl_lds16(A + aoff[l2] + t * 64, LS[t] + adl + l2 * 4096);
#pragma unroll
    for (int l2 = 0; l2 < 2; ++l2) gl_lds16(B + boff[l2] + t * 64, LS[t] + bdl + l2 * 4096);
  }
  waitvm<6>();
  __builtin_amdgcn_s_barrier();

  int s = 0;
  for (int kt = 0; kt < 32; ++kt) {
    if (kt < 30) {
      const int s2 = (s == 0) ? 2 : s - 1;
      const int k2 = (kt + 2) * 64;
#pragma unroll
      for (int l2 = 0; l2 < 4; ++l2) gl_lds16(A + aoff[l2] + k2, LS[s2] + adl + l2 * 4096);
#pragma unroll
      for (int l2 = 0; l2 < 2; ++l2) gl_lds16(B + boff[l2] + k2, LS[s2] + bdl + l2 * 4096);
    }
    const char* base = (const char*)LS[s];
#pragma unroll
    for (int h = 0; h < 2; ++h) {
      bf16x8 af[4];
#pragma unroll
      for (int ai = 0; ai < 4; ++ai) {
        int r = wm + ai * 16 + lr;
        af[ai] = *(const bf16x8*)(base + r * 128 + ((h * 64 + 16 * g) ^ kx));
      }
      __builtin_amdgcn_s_setprio(1);
#pragma unroll
      for (int bj = 0; bj < 4; ++bj) {
        int rb = wn + bj * 16 + lr;
        bf16x8 bfr = *(const bf16x8*)(base + 32768 + rb * 128 + ((h * 64 + 16 * g) ^ kx));
#pragma unroll
        for (int ai = 0; ai < 4; ++ai)
          acc[ai][bj] = __builtin_amdgcn_mfma_f32_16x16x32_bf16(af[ai], bfr, acc[ai][bj], 0, 0, 0);
      }
      __builtin_amdgcn_s_setprio(0);
    }
    if (kt < 30)       waitvm<6>();
    else if (kt == 30) waitvm<0>();
    __builtin_amdgcn_s_barrier();
    s = (s == 2) ? 0 : s + 1;
  }

  const int rbase = g * 4;
#pragma unroll
  for (int bj = 0; bj < 4; ++bj) {
    const int gn = n0 + wn + bj * 16 + lr;
    const float bv_ = bo[gn];
#pragma unroll
    for (int ai = 0; ai < 4; ++ai)
#pragma unroll
      for (int r = 0; r < 4; ++r) {
        int gm = m0 + wm + ai * 16 + rbase + r;
        outf[(size_t)gm * 2048 + gn] = acc[ai][bj][r] + bv_;
      }
  }
}

// ---------------- flash attention (causal) ----------------
// 512 blocks of 256 threads; bid -> bh = bid&31 (XCD-grouped), qt = 15-(bid>>5).
// 4 waves x 32 q-rows; KV tile 64, double-buffered, gl_lds staging pre-swizzled.
// P-pack via v_cvt_pk_bf16_f32; per-lane row-sum partials; defer-max; sigma'd V^T.
__global__ __launch_bounds__(256) void attn_kernel(
    const u16* __restrict__ qg, const u16* __restrict__ kg,
    const u16* __restrict__ vtg, u16* __restrict__ y) {
  __shared__ u16 Kb[2][64 * 128];
  __shared__ u16 Vb[2][128 * 64];
  __shared__ u16 Pl[4][32 * 64];
  const int tid = threadIdx.x, lane = tid & 63, w = tid >> 6;
  const int bid = blockIdx.x;
  const int bh = bid & 31, qt = 15 - (bid >> 5);
  const int b = bh >> 4, h = bh & 15;
  const int lr = lane & 15, lk = (lane >> 4) * 8;
  const u16* Qp = qg + (size_t)bh * (2048 * 128);
  const u16* Kp = kg + (size_t)bh * (2048 * 128);
  const u16* Vp = vtg + (size_t)bh * (128 * 2048);

  int koff[4], voff[4], dstc[4];
#pragma unroll
  for (int c = 0; c < 4; ++c) {
    int ci = c * 256 + tid;
    dstc[c] = ci * 8;
    int kr = ci >> 4, kj = ci & 15;
    koff[c] = kr * 128 + (kj ^ (kr & 7)) * 8;
    int vd = ci >> 3, vj = ci & 7;
    voff[c] = vd * 2048 + (vj ^ (vd & 7)) * 8;
  }
  const int kxor = (lr & 7) << 4;
  const int rbase = (lane >> 4) * 4;
  const f32x4 zero = {0.f, 0.f, 0.f, 0.f};

  const int q0 = qt * 128;
  const int qw = q0 + w * 32;
  const int nt = 2 * qt + 2;

  bf16x8 qf[2][4];
#pragma unroll
  for (int s = 0; s < 2; ++s)
#pragma unroll
    for (int i = 0; i < 4; ++i)
      qf[s][i] = *(const bf16x8*)(Qp + (size_t)(qw + s * 16 + lr) * 128 + i * 32 + lk);

  f32x4 o[2][8];
#pragma unroll
  for (int s = 0; s < 2; ++s)
#pragma unroll
    for (int f = 0; f < 8; ++f) o[s][f] = zero;
  float mrow[2][4], lrow[2][4];
#pragma unroll
  for (int s = 0; s < 2; ++s)
#pragma unroll
    for (int r = 0; r < 4; ++r) { mrow[s][r] = -1e30f; lrow[s][r] = 0.f; }

#pragma unroll
  for (int c = 0; c < 4; ++c) gl_lds16(Kp + koff[c], Kb[0] + dstc[c]);
#pragma unroll
  for (int c = 0; c < 4; ++c) gl_lds16(Vp + voff[c], Vb[0] + dstc[c]);
  __syncthreads();

  int cur = 0;
  for (int t = 0; t < nt; ++t) {
    const int s0 = t * 64;
    if (t + 1 < nt) {
      const size_t skn = (size_t)(s0 + 64) * 128;
#pragma unroll
      for (int c = 0; c < 4; ++c) gl_lds16(Kp + skn + koff[c], Kb[cur ^ 1] + dstc[c]);
#pragma unroll
      for (int c = 0; c < 4; ++c) gl_lds16(Vp + (s0 + 64) + voff[c], Vb[cur ^ 1] + dstc[c]);
    }
    if (s0 <= qw + 31) {
      const char* Kc = (const char*)Kb[cur];
      f32x4 sf[2][4];
      __builtin_amdgcn_s_setprio(1);
#pragma unroll
      for (int sj = 0; sj < 4; ++sj) {
        f32x4 a0 = zero, a1 = zero;
#pragma unroll
        for (int i = 0; i < 4; ++i) {
          bf16x8 kf = *(const bf16x8*)(Kc + ((((sj * 16 + lr) * 256) + (i * 32 + lk) * 2) ^ kxor));
          a0 = __builtin_amdgcn_mfma_f32_16x16x32_bf16(qf[0][i], kf, a0, 0, 0, 0);
          a1 = __builtin_amdgcn_mfma_f32_16x16x32_bf16(qf[1][i], kf, a1, 0, 0, 0);
        }
        sf[0][sj] = a0; sf[1][sj] = a1;
      }
      __builtin_amdgcn_s_setprio(0);

      char* Pc = (char*)Pl[w];
      const bool diag = (s0 + 63 > qw);
      float pmax[2][4];
      bool need = false;
#pragma unroll
      for (int s = 0; s < 2; ++s)
#pragma unroll
        for (int r = 0; r < 4; ++r) {
          if (diag) {
            const int rq = qw + s * 16 + rbase + r;
#pragma unroll
            for (int sj = 0; sj < 4; ++sj)
              if (s0 + sj * 16 + lr > rq) sf[s][sj][r] = -1e30f;
          }
          float pm = fmaxf(fmaxf(sf[s][0][r], sf[s][1][r]),
                           fmaxf(sf[s][2][r], sf[s][3][r]));
          pmax[s][r] = pm;
          need |= (pm > mrow[s][r] + 8.f);
        }
      if (__any(need)) {
#pragma unroll
        for (int s = 0; s < 2; ++s)
#pragma unroll
          for (int r = 0; r < 4; ++r) {
            float pm = pmax[s][r];
            pm = fmaxf(pm, __shfl_xor(pm, 1));
            pm = fmaxf(pm, __shfl_xor(pm, 2));
            pm = fmaxf(pm, __shfl_xor(pm, 4));
            pm = fmaxf(pm, __shfl_xor(pm, 8));
            float mnew = fmaxf(mrow[s][r], pm);
            float sfac = __builtin_amdgcn_exp2f(mrow[s][r] - mnew);
            mrow[s][r] = mnew;
            lrow[s][r] *= sfac;
#pragma unroll
            for (int f = 0; f < 8; ++f) o[s][f][r] *= sfac;
          }
      }
#pragma unroll
      for (int s = 0; s < 2; ++s)
#pragma unroll
        for (int r = 0; r < 4; ++r) {
          const int prow = s * 16 + rbase + r;
          float p0 = __builtin_amdgcn_exp2f(sf[s][0][r] - mrow[s][r]);
          float p1 = __builtin_amdgcn_exp2f(sf[s][1][r] - mrow[s][r]);
          float p2 = __builtin_amdgcn_exp2f(sf[s][2][r] - mrow[s][r]);
          float p3 = __builtin_amdgcn_exp2f(sf[s][3][r] - mrow[s][r]);
          lrow[s][r] += (p0 + p1) + (p2 + p3);
          uint32_t lo, hi;
          asm("v_cvt_pk_bf16_f32 %0, %1, %2" : "=v"(lo) : "v"(p0), "v"(p1));
          asm("v_cvt_pk_bf16_f32 %0, %1, %2" : "=v"(hi) : "v"(p2), "v"(p3));
          uint32_t* pp = (uint32_t*)(Pc + ((prow * 128 + lr * 8) ^ ((prow & 7) << 4)));
          pp[0] = lo; pp[1] = hi;
        }

      const char* Vc = (const char*)Vb[cur];
      __builtin_amdgcn_s_setprio(1);
#pragma unroll
      for (int st = 0; st < 2; ++st) {
        bf16x8 pf0 = *(const bf16x8*)(Pc + (((lr * 128) + (st * 32 + lk) * 2) ^ kxor));
        bf16x8 pf1 = *(const bf16x8*)(Pc + ((((16 + lr) * 128) + (st * 32 + lk) * 2) ^ kxor));
#pragma unroll
        for (int f = 0; f < 8; ++f) {
          bf16x8 vf = *(const bf16x8*)(Vc + ((((f * 16 + lr) * 128) + (st * 32 + lk) * 2) ^ kxor));
          o[0][f] = __builtin_amdgcn_mfma_f32_16x16x32_bf16(pf0, vf, o[0][f], 0, 0, 0);
          o[1][f] = __builtin_amdgcn_mfma_f32_16x16x32_bf16(pf1, vf, o[1][f], 0, 0, 0);
        }
      }
      __builtin_amdgcn_s_setprio(0);
    }
    __syncthreads();
    cur ^= 1;
  }

#pragma unroll
  for (int s = 0; s < 2; ++s)
#pragma unroll
    for (int r = 0; r < 4; ++r) {
      float l = lrow[s][r];
      l += __shfl_xor(l, 1);
      l += __shfl_xor(l, 2);
      l += __shfl_xor(l, 4);
      l += __shfl_xor(l, 8);
      const float rinv = __builtin_amdgcn_rcpf(l);
      const int row = qw + s * 16 + rbase + r;
#pragma unroll
      for (int f = 0; f < 8; ++f)
        y[((size_t)b * 2048 + row) * 2048 + h * 128 + f * 16 + lr] =
            f2b(o[s][f][r] * rinv);
    }
}

// ---------------- launch ----------------

extern "C" void kernel_launch(void* const* d_in, const int* in_sizes, int n_in,
                              void* d_out, int out_size, void* d_ws, size_t ws_size,
                              hipStream_t stream) {
  const float* x  = (const float*)d_in[0];
  const float* Wq = (const float*)d_in[1];
  const float* bq = (const float*)d_in[2];
  const float* Wk = (const float*)d_in[3];
  const float* bk = (const float*)d_in[4];
  const float* Wv = (const float*)d_in[5];
  const float* bv = (const float*)d_in[6];
  const float* Wo = (const float*)d_in[7];
  const float* bo = (const float*)d_in[8];
  float* out = (float*)d_out;
  char* ws = (char*)d_ws;

  u16* xb  = (u16*)(ws + 0);          // 16 MB; reused as yb after QKV GEMM
  u16* Wt  = (u16*)(ws + 16777216);   // 24 MB; front 8 MB reused as Wot, next 16 MB as vtb
  u16* qb  = (u16*)(ws + 41943040);   // 16 MB
  u16* kb  = (u16*)(ws + 58720256);   // 16 MB
  u16* vb  = (u16*)(ws + 75497472);   // 16 MB (total 88 MB)
  u16* Wot = Wt;                      // [2048][2048] bf16 = 8 MB
  u16* vtb = (u16*)(ws + 25165824);   // [B,H,128,T] bf16 = 16 MB
  u16* yb  = xb;

  prep_kernel<<<9728, 256, 0, stream>>>(x, xb, Wq, Wk, Wv, Wt);
  gemm_qkv_kernel<<<256, 512, 0, stream>>>(xb, Wt, qb, kb, vb, bq, bk, bv);
  trans_wo_kernel<<<dim3(32, 16), 256, 0, stream>>>(Wo, Wot);
  transpose_v_kernel<<<dim3(32, 32), 256, 0, stream>>>(vb, vtb);
  attn_kernel<<<512, 256, 0, stream>>>(qb, kb, vtb, yb);
  gemm_out_kernel<<<256, 512, 0, stream>>>(yb, Wot, out, bo);
}

// Round 17
// 263.579 us; speedup vs baseline: 1.1810x; 1.0404x over previous
//
#include <hip/hip_runtime.h>
#include <stdint.h>

typedef unsigned short u16;
typedef unsigned int u32;
typedef __attribute__((ext_vector_type(4))) u16 u16x4;
typedef __attribute__((ext_vector_type(8))) u16 u16x8;
typedef __attribute__((ext_vector_type(4))) u32 u32x4;
typedef __attribute__((ext_vector_type(8))) __bf16 bf16x8;
typedef __attribute__((ext_vector_type(4))) float f32x4;
typedef __attribute__((ext_vector_type(16))) float f32x16;

#define D_MODEL 2048
#define N_HEADS 16
#define HEAD_DIM 128
#define BATCH 2
#define SEQ 2048
#define M_TOT (BATCH*SEQ)          // 4096
#define N_QKV (3*D_MODEL)          // 6144

__device__ __forceinline__ u16 f2b(float f) {
  union { float f; uint32_t u; } c; c.f = f;
  uint32_t u = c.u;
  uint32_t r = (u + 0x7fffu + ((u >> 16) & 1u)) >> 16;
  return (u16)r;
}

__device__ __forceinline__ void gl_lds16(const u16* g, u16* l) {
  __builtin_amdgcn_global_load_lds(
      (const __attribute__((address_space(1))) uint32_t*)g,
      (__attribute__((address_space(3))) uint32_t*)l, 16, 0, 0);
}

template <int N> __device__ __forceinline__ void waitvm() {
  if constexpr (N == 7)      asm volatile("s_waitcnt vmcnt(7)" ::: "memory");
  else if constexpr (N == 6) asm volatile("s_waitcnt vmcnt(6)" ::: "memory");
  else if constexpr (N == 5) asm volatile("s_waitcnt vmcnt(5)" ::: "memory");
  else                       asm volatile("s_waitcnt vmcnt(0)" ::: "memory");
}
__device__ __forceinline__ void lgkm0() {
  asm volatile("s_waitcnt lgkmcnt(0)" ::: "memory");
}
__device__ __forceinline__ u32 cvtpk(float a, float b) {
  u32 r;
  asm("v_cvt_pk_bf16_f32 %0, %1, %2" : "=v"(r) : "v"(a), "v"(b));
  return r;
}

// ---------------- prep kernel: Wq/Wk/Wv transpose only ----------------
// (x is consumed as f32 directly by gemm_qkv now; x-cast kernel deleted.)
__global__ __launch_bounds__(256) void prep_kernel(
    const float* __restrict__ Wq, const float* __restrict__ Wk,
    const float* __restrict__ Wv, u16* __restrict__ Wt) {
  __shared__ u16 Tl[128][72];
  const int bid = blockIdx.x, tid = threadIdx.x;
  const int k0 = (bid & 31) * 64;
  const int hh = bid >> 5;           // 0..47 = qkv*16+h
  const int qkv = hh >> 4, h = hh & 15;
  const float* src = (qkv == 0 ? Wq : qkv == 1 ? Wk : Wv) + (size_t)h * 2048 * 128;
  for (int it = 0; it < 32; ++it) {
    int idx = it * 256 + tid;
    int k = idx >> 7, d = idx & 127;
    Tl[d][k] = f2b(src[(size_t)(k0 + k) * 128 + d]);
  }
  __syncthreads();
  for (int it = 0; it < 32; ++it) {
    int idx = it * 256 + tid;
    int d = idx >> 6, kk = idx & 63;
    Wt[(size_t)(hh * 128 + d) * 2048 + k0 + kk] = Tl[d][kk];
  }
}

// ---------------- merged post-QKV transposes ----------------
// bid < 512: Wo -> Wot (transposed K-major; Wot aliases Wt -> must be after gemm_qkv).
// bid >= 512: vb [B,H,T,128] -> vt [B,H,128,T] with sigma(t)=(t&15)*4+(t>>4) per 64-tile.
__global__ __launch_bounds__(256) void post_transpose_kernel(
    const float* __restrict__ Wo, u16* __restrict__ Wot,
    const u16* __restrict__ vb, u16* __restrict__ vt) {
  __shared__ u16 Tl[128 * 72];
  const int bid = blockIdx.x, tid = threadIdx.x;
  if (bid < 512) {
    const int k0 = (bid & 31) * 64;
    const int n0 = (bid >> 5) * 128;
    for (int it = 0; it < 32; ++it) {
      int idx = it * 256 + tid;
      int k = idx >> 7, n = idx & 127;
      Tl[n * 72 + k] = f2b(Wo[(size_t)(k0 + k) * 2048 + n0 + n]);
    }
    __syncthreads();
    for (int it = 0; it < 32; ++it) {
      int idx = it * 256 + tid;
      int d = idx >> 6, kk = idx & 63;
      Wot[(size_t)(n0 + d) * 2048 + k0 + kk] = Tl[d * 72 + kk];
    }
    return;
  }
  const int rel = bid - 512;
  const int t0 = (rel & 31) * 64;
  const int bh = rel >> 5;
  const u16* src = vb + (size_t)bh * 2048 * 128;
  u16* dstp = vt + (size_t)bh * 128 * 2048;
#pragma unroll
  for (int c = 0; c < 4; ++c) {
    int ci = c * 256 + tid;
    int tr = ci >> 4, d0 = (ci & 15) * 8;
    u16x8 v = *(const u16x8*)(src + (size_t)(t0 + tr) * 128 + d0);
#pragma unroll
    for (int e = 0; e < 8; ++e) Tl[(d0 + e) * 72 + tr] = v[e];
  }
  __syncthreads();
#pragma unroll
  for (int it = 0; it < 32; ++it) {
    int idx = it * 256 + tid;
    int d = idx >> 6, tt = idx & 63;
    dstp[(size_t)d * 2048 + t0 + ((tt & 15) * 4 + (tt >> 4))] = Tl[d * 72 + tt];
  }
}

// ---------- QKV GEMM: 256x384 tile, 32x32x16 MFMA, BK=32, ring-3, counted vmcnt ----------
// r9/r16 geometry (107 us, 43% MfmaUtil). 512 thr = 8 waves (2M x 4N),
// wave tile 128x96 = 4x3 32x32 frags. LDS ring-3 {A[256][32], B[384][32]} 120 KB,
// row-pair interleaved layout (granule g of row r at slot (r>>1)*8 + (x^((r>>1)&7)),
// x=((r&1)<<2)|g). B staged by gl_lds (pre-swizzled source, tid*16-linear dest).
// NEW (r17): A staged DIRECTLY FROM f32 x -- 4 global_load_dwordx4 (compiler
// auto-waits dest regs), 8 v_cvt_pk_bf16_f32 (RTNE == f2b), 2 ds_write_b128 into
// the swizzled slot (ds_write has full addr freedom). Deletes the 25-us x-cast.
// Pipeline: load A(kt+2) at kt; cvt+write A(kt+1) at kt; lgkmcnt(0) before each
// barrier; end-of-tile vmcnt(7) pins B(kt+1) ({A,B}(kt+2)=7 still in flight).
__global__ __launch_bounds__(512, 2) void gemm_qkv_kernel(
    const float* __restrict__ X, const u16* __restrict__ B,
    u16* __restrict__ qo, u16* __restrict__ ko, u16* __restrict__ vo,
    const float* __restrict__ bq, const float* __restrict__ bk, const float* __restrict__ bv) {
  __shared__ u16 LS[3][20480];   // A: [0,8192) u16, B: [8192,20480)
  const int bid0 = blockIdx.x;
  const int gid = (bid0 & 7) * 32 + (bid0 >> 3);   // XCD-chunked (256 blocks)
  const int G = gid >> 4, l = gid & 15;            // 16 groups of 4mt x 4nt
  const int m0 = ((G & 3) * 4 + (l & 3)) * 256;
  const int n0 = ((G >> 2) * 4 + (l >> 2)) * 384;

  const int tid = threadIdx.x, lane = tid & 63, w = tid >> 6;
  const int wm = (w >> 2) * 128, wn = (w & 3) * 96;
  const int l31 = lane & 31, g2 = lane >> 5;

  // A source (f32 x, element offsets identical to the old bf16 indexing)
  // chunk ci: row-pair t=ci>>3, x=(ci&7)^(t&7) -> row m0+2t+(x>>2), col (x&3)*8
  int aoff[2], boff[3];
#pragma unroll
  for (int l2 = 0; l2 < 2; ++l2) {
    int ci = l2 * 512 + tid, t = ci >> 3, x = (ci & 7) ^ (t & 7);
    aoff[l2] = (m0 + 2 * t + (x >> 2)) * 2048 + (x & 3) * 8;
  }
#pragma unroll
  for (int l2 = 0; l2 < 3; ++l2) {
    int ci = l2 * 512 + tid, t = ci >> 3, x = (ci & 7) ^ (t & 7);
    boff[l2] = (n0 + 2 * t + (x >> 2)) * 2048 + (x & 3) * 8;
  }
  const int adl = tid * 8;            // u16 offset of chunk0 dest; chunk1 at +4096
  const int bdl = 8192 + tid * 8;

  f32x16 acc[4][3];
#pragma unroll
  for (int ai = 0; ai < 4; ++ai)
#pragma unroll
    for (int bj = 0; bj < 3; ++bj)
#pragma unroll
      for (int e = 0; e < 16; ++e) acc[ai][bj][e] = 0.f;

  // prologue: load A(0)->t*, A(1)->rc*; stage B(0),B(1); write A(0) to slot0
  f32x4 t0a = *(const f32x4*)(X + aoff[0]);
  f32x4 t0b = *(const f32x4*)(X + aoff[0] + 4);
  f32x4 t1a = *(const f32x4*)(X + aoff[1]);
  f32x4 t1b = *(const f32x4*)(X + aoff[1] + 4);
  f32x4 rc0a = *(const f32x4*)(X + aoff[0] + 32);
  f32x4 rc0b = *(const f32x4*)(X + aoff[0] + 36);
  f32x4 rc1a = *(const f32x4*)(X + aoff[1] + 32);
  f32x4 rc1b = *(const f32x4*)(X + aoff[1] + 36);
#pragma unroll
  for (int t = 0; t < 2; ++t)
#pragma unroll
    for (int l2 = 0; l2 < 3; ++l2)
      gl_lds16(B + boff[l2] + t * 32, LS[t] + bdl + l2 * 4096);
  {
    u32x4 w0 = {cvtpk(t0a[0], t0a[1]), cvtpk(t0a[2], t0a[3]),
                cvtpk(t0b[0], t0b[1]), cvtpk(t0b[2], t0b[3])};
    u32x4 w1 = {cvtpk(t1a[0], t1a[1]), cvtpk(t1a[2], t1a[3]),
                cvtpk(t1b[0], t1b[1]), cvtpk(t1b[2], t1b[3])};
    *(__shared__ u32x4*)(LS[0] + adl) = w0;
    *(__shared__ u32x4*)(LS[0] + adl + 4096) = w1;
  }
  waitvm<5>();                         // B(0) landed (B(1)=3, A-reg loads auto-tracked... conservative)
  lgkm0();
  __builtin_amdgcn_s_barrier();

  int s = 0;
  for (int kt = 0; kt < 64; ++kt) {
    const int sw = (s == 2) ? 0 : s + 1;           // slot for kt+1 (A write)
    f32x4 rn0a, rn0b, rn1a, rn1b;
    if (kt < 62) {
      const int s2 = (s == 0) ? 2 : s - 1;         // slot for kt+2 (B stage)
      const int k2 = (kt + 2) * 32;
      rn0a = *(const f32x4*)(X + aoff[0] + k2);
      rn0b = *(const f32x4*)(X + aoff[0] + k2 + 4);
      rn1a = *(const f32x4*)(X + aoff[1] + k2);
      rn1b = *(const f32x4*)(X + aoff[1] + k2 + 4);
#pragma unroll
      for (int l2 = 0; l2 < 3; ++l2) gl_lds16(B + boff[l2] + k2, LS[s2] + bdl + l2 * 4096);
    }
    if (kt < 63) {                      // write A(kt+1) into slot sw (free since kt-2)
      u32x4 w0 = {cvtpk(rc0a[0], rc0a[1]), cvtpk(rc0a[2], rc0a[3]),
                  cvtpk(rc0b[0], rc0b[1]), cvtpk(rc0b[2], rc0b[3])};
      u32x4 w1 = {cvtpk(rc1a[0], rc1a[1]), cvtpk(rc1a[2], rc1a[3]),
                  cvtpk(rc1b[0], rc1b[1]), cvtpk(rc1b[2], rc1b[3])};
      *(__shared__ u32x4*)(LS[sw] + adl) = w0;
      *(__shared__ u32x4*)(LS[sw] + adl + 4096) = w1;
    }
    const char* base = (const char*)LS[s];
#pragma unroll
    for (int kk = 0; kk < 2; ++kk) {
      bf16x8 af[4];
#pragma unroll
      for (int ai = 0; ai < 4; ++ai) {
        int r = wm + ai * 32 + l31;
        int x = ((r & 1) << 2) | (2 * kk + g2);
        af[ai] = *(const bf16x8*)(base + (r >> 1) * 128 + 16 * (x ^ ((r >> 1) & 7)));
      }
      __builtin_amdgcn_s_setprio(1);
#pragma unroll
      for (int bj = 0; bj < 3; ++bj) {
        int rb = wn + bj * 32 + l31;
        int xb2 = ((rb & 1) << 2) | (2 * kk + g2);
        bf16x8 bfr = *(const bf16x8*)(base + 16384 + (rb >> 1) * 128 + 16 * (xb2 ^ ((rb >> 1) & 7)));
#pragma unroll
        for (int ai = 0; ai < 4; ++ai)
          acc[ai][bj] = __builtin_amdgcn_mfma_f32_32x32x16_bf16(af[ai], bfr, acc[ai][bj], 0, 0, 0);
      }
      __builtin_amdgcn_s_setprio(0);
    }
    if (kt < 62)       waitvm<7>();     // B(kt+1) landed; {A,B}(kt+2) in flight
    else if (kt == 62) waitvm<0>();
    lgkm0();
    __builtin_amdgcn_s_barrier();
    rc0a = rn0a; rc0b = rn0b; rc1a = rn1a; rc1b = rn1b;
    s = sw;
  }

  // epilogue: C/D 32x32 layout col=lane&31, row=(reg&3)+8*(reg>>2)+4*(lane>>5)
  const float qscale = 0.08838834764831845f * 1.4426950408889634f;  // 1/sqrt(128)*log2e
#pragma unroll
  for (int bj = 0; bj < 3; ++bj) {
    const int n = n0 + wn + bj * 32 + l31;
    const int qkv = n >> 11, hh = (n >> 7) & 15, d = n & 127;
    const float* bias = (qkv == 0) ? bq : (qkv == 1) ? bk : bv;
    u16* dst = (qkv == 0) ? qo : (qkv == 1) ? ko : vo;
    const float bv_ = bias[n & 2047];
#pragma unroll
    for (int ai = 0; ai < 4; ++ai)
#pragma unroll
      for (int e = 0; e < 16; ++e) {
        int row = (e & 3) + 8 * (e >> 2) + 4 * g2;
        int gm = m0 + wm + ai * 32 + row;
        float val = acc[ai][bj][e] + bv_;
        if (qkv == 0) val *= qscale;
        int b = gm >> 11, t = gm & 2047;
        dst[((size_t)(b * 16 + hh) * 2048 + t) * 128 + d] = f2b(val);
      }
  }
}

// ---------- Output GEMM: 256x128 tile, 16x16x32 MFMA, BK=64, ring-3, counted vmcnt ----------
__global__ __launch_bounds__(512, 2) void gemm_out_kernel(
    const u16* __restrict__ A, const u16* __restrict__ B,
    float* __restrict__ outf, const float* __restrict__ bo) {
  __shared__ u16 LS[3][24576];   // A: [0,16384) u16, B: [16384,24576)
  const int bid0 = blockIdx.x;
  const int gid = (bid0 & 7) * 32 + (bid0 >> 3);   // 256 blocks
  const int G = gid >> 4, l = gid & 15;
  const int m0 = ((G & 3) * 4 + (l & 3)) * 256;
  const int n0 = ((G >> 2) * 4 + (l >> 2)) * 128;

  const int tid = threadIdx.x, lane = tid & 63, w = tid >> 6;
  const int wm = (w >> 1) * 64, wn = (w & 1) * 64;
  const int lr = lane & 15, g = lane >> 4;
  const int kx = (lr & 7) << 4;

  int aoff[4], boff[2];
#pragma unroll
  for (int l2 = 0; l2 < 4; ++l2) {
    int ci = l2 * 512 + tid, r = ci >> 3, gj = ci & 7;
    aoff[l2] = (m0 + r) * 2048 + (gj ^ (r & 7)) * 8;
  }
#pragma unroll
  for (int l2 = 0; l2 < 2; ++l2) {
    int ci = l2 * 512 + tid, r = ci >> 3, gj = ci & 7;
    boff[l2] = (n0 + r) * 2048 + (gj ^ (r & 7)) * 8;
  }
  const int adl = tid * 8;
  const int bdl = 16384 + tid * 8;

  f32x4 acc[4][4];
  const f32x4 zero = {0.f, 0.f, 0.f, 0.f};
#pragma unroll
  for (int ai = 0; ai < 4; ++ai)
#pragma unroll
    for (int bj = 0; bj < 4; ++bj) acc[ai][bj] = zero;

#pragma unroll
  for (int t = 0; t < 2; ++t) {
#pragma unroll
    for (int l2 = 0; l2 < 4; ++l2) gl_lds16(A + aoff[l2] + t * 64, LS[t] + adl + l2 * 4096);
#pragma unroll
    for (int l2 = 0; l2 < 2; ++l2) gl_lds16(B + boff[l2] + t * 64, LS[t] + bdl + l2 * 4096);
  }
  waitvm<6>();
  __builtin_amdgcn_s_barrier();

  int s = 0;
  for (int kt = 0; kt < 32; ++kt) {
    if (kt < 30) {
      const int s2 = (s == 0) ? 2 : s - 1;
      const int k2 = (kt + 2) * 64;
#pragma unroll
      for (int l2 = 0; l2 < 4; ++l2) gl_lds16(A + aoff[l2] + k2, LS[s2] + adl + l2 * 4096);
#pragma unroll
      for (int l2 = 0; l2 < 2; ++l2) gl_lds16(B + boff[l2] + k2, LS[s2] + bdl + l2 * 4096);
    }
    const char* base = (const char*)LS[s];
#pragma unroll
    for (int h = 0; h < 2; ++h) {
      bf16x8 af[4];
#pragma unroll
      for (int ai = 0; ai < 4; ++ai) {
        int r = wm + ai * 16 + lr;
        af[ai] = *(const bf16x8*)(base + r * 128 + ((h * 64 + 16 * g) ^ kx));
      }
      __builtin_amdgcn_s_setprio(1);
#pragma unroll
      for (int bj = 0; bj < 4; ++bj) {
        int rb = wn + bj * 16 + lr;
        bf16x8 bfr = *(const bf16x8*)(base + 32768 + rb * 128 + ((h * 64 + 16 * g) ^ kx));
#pragma unroll
        for (int ai = 0; ai < 4; ++ai)
          acc[ai][bj] = __builtin_amdgcn_mfma_f32_16x16x32_bf16(af[ai], bfr, acc[ai][bj], 0, 0, 0);
      }
      __builtin_amdgcn_s_setprio(0);
    }
    if (kt < 30)       waitvm<6>();
    else if (kt == 30) waitvm<0>();
    __builtin_amdgcn_s_barrier();
    s = (s == 2) ? 0 : s + 1;
  }

  const int rbase = g * 4;
#pragma unroll
  for (int bj = 0; bj < 4; ++bj) {
    const int gn = n0 + wn + bj * 16 + lr;
    const float bv_ = bo[gn];
#pragma unroll
    for (int ai = 0; ai < 4; ++ai)
#pragma unroll
      for (int r = 0; r < 4; ++r) {
        int gm = m0 + wm + ai * 16 + rbase + r;
        outf[(size_t)gm * 2048 + gn] = acc[ai][bj][r] + bv_;
      }
  }
}

// ---------------- flash attention (causal) ----------------
__global__ __launch_bounds__(256) void attn_kernel(
    const u16* __restrict__ qg, const u16* __restrict__ kg,
    const u16* __restrict__ vtg, u16* __restrict__ y) {
  __shared__ u16 Kb[2][64 * 128];
  __shared__ u16 Vb[2][128 * 64];
  __shared__ u16 Pl[4][32 * 64];
  const int tid = threadIdx.x, lane = tid & 63, w = tid >> 6;
  const int bid = blockIdx.x;
  const int bh = bid & 31, qt = 15 - (bid >> 5);
  const int b = bh >> 4, h = bh & 15;
  const int lr = lane & 15, lk = (lane >> 4) * 8;
  const u16* Qp = qg + (size_t)bh * (2048 * 128);
  const u16* Kp = kg + (size_t)bh * (2048 * 128);
  const u16* Vp = vtg + (size_t)bh * (128 * 2048);

  int koff[4], voff[4], dstc[4];
#pragma unroll
  for (int c = 0; c < 4; ++c) {
    int ci = c * 256 + tid;
    dstc[c] = ci * 8;
    int kr = ci >> 4, kj = ci & 15;
    koff[c] = kr * 128 + (kj ^ (kr & 7)) * 8;
    int vd = ci >> 3, vj = ci & 7;
    voff[c] = vd * 2048 + (vj ^ (vd & 7)) * 8;
  }
  const int kxor = (lr & 7) << 4;
  const int rbase = (lane >> 4) * 4;
  const f32x4 zero = {0.f, 0.f, 0.f, 0.f};

  const int q0 = qt * 128;
  const int qw = q0 + w * 32;
  const int nt = 2 * qt + 2;

  bf16x8 qf[2][4];
#pragma unroll
  for (int s = 0; s < 2; ++s)
#pragma unroll
    for (int i = 0; i < 4; ++i)
      qf[s][i] = *(const bf16x8*)(Qp + (size_t)(qw + s * 16 + lr) * 128 + i * 32 + lk);

  f32x4 o[2][8];
#pragma unroll
  for (int s = 0; s < 2; ++s)
#pragma unroll
    for (int f = 0; f < 8; ++f) o[s][f] = zero;
  float mrow[2][4], lrow[2][4];
#pragma unroll
  for (int s = 0; s < 2; ++s)
#pragma unroll
    for (int r = 0; r < 4; ++r) { mrow[s][r] = -1e30f; lrow[s][r] = 0.f; }

#pragma unroll
  for (int c = 0; c < 4; ++c) gl_lds16(Kp + koff[c], Kb[0] + dstc[c]);
#pragma unroll
  for (int c = 0; c < 4; ++c) gl_lds16(Vp + voff[c], Vb[0] + dstc[c]);
  __syncthreads();

  int cur = 0;
  for (int t = 0; t < nt; ++t) {
    const int s0 = t * 64;
    if (t + 1 < nt) {
      const size_t skn = (size_t)(s0 + 64) * 128;
#pragma unroll
      for (int c = 0; c < 4; ++c) gl_lds16(Kp + skn + koff[c], Kb[cur ^ 1] + dstc[c]);
#pragma unroll
      for (int c = 0; c < 4; ++c) gl_lds16(Vp + (s0 + 64) + voff[c], Vb[cur ^ 1] + dstc[c]);
    }
    if (s0 <= qw + 31) {
      const char* Kc = (const char*)Kb[cur];
      f32x4 sf[2][4];
      __builtin_amdgcn_s_setprio(1);
#pragma unroll
      for (int sj = 0; sj < 4; ++sj) {
        f32x4 a0 = zero, a1 = zero;
#pragma unroll
        for (int i = 0; i < 4; ++i) {
          bf16x8 kf = *(const bf16x8*)(Kc + ((((sj * 16 + lr) * 256) + (i * 32 + lk) * 2) ^ kxor));
          a0 = __builtin_amdgcn_mfma_f32_16x16x32_bf16(qf[0][i], kf, a0, 0, 0, 0);
          a1 = __builtin_amdgcn_mfma_f32_16x16x32_bf16(qf[1][i], kf, a1, 0, 0, 0);
        }
        sf[0][sj] = a0; sf[1][sj] = a1;
      }
      __builtin_amdgcn_s_setprio(0);

      char* Pc = (char*)Pl[w];
      const bool diag = (s0 + 63 > qw);
      float pmax[2][4];
      bool need = false;
#pragma unroll
      for (int s = 0; s < 2; ++s)
#pragma unroll
        for (int r = 0; r < 4; ++r) {
          if (diag) {
            const int rq = qw + s * 16 + rbase + r;
#pragma unroll
            for (int sj = 0; sj < 4; ++sj)
              if (s0 + sj * 16 + lr > rq) sf[s][sj][r] = -1e30f;
          }
          float pm = fmaxf(fmaxf(sf[s][0][r], sf[s][1][r]),
                           fmaxf(sf[s][2][r], sf[s][3][r]));
          pmax[s][r] = pm;
          need |= (pm > mrow[s][r] + 8.f);
        }
      if (__any(need)) {
#pragma unroll
        for (int s = 0; s < 2; ++s)
#pragma unroll
          for (int r = 0; r < 4; ++r) {
            float pm = pmax[s][r];
            pm = fmaxf(pm, __shfl_xor(pm, 1));
            pm = fmaxf(pm, __shfl_xor(pm, 2));
            pm = fmaxf(pm, __shfl_xor(pm, 4));
            pm = fmaxf(pm, __shfl_xor(pm, 8));
            float mnew = fmaxf(mrow[s][r], pm);
            float sfac = __builtin_amdgcn_exp2f(mrow[s][r] - mnew);
            mrow[s][r] = mnew;
            lrow[s][r] *= sfac;
#pragma unroll
            for (int f = 0; f < 8; ++f) o[s][f][r] *= sfac;
          }
      }
#pragma unroll
      for (int s = 0; s < 2; ++s)
#pragma unroll
        for (int r = 0; r < 4; ++r) {
          const int prow = s * 16 + rbase + r;
          float p0 = __builtin_amdgcn_exp2f(sf[s][0][r] - mrow[s][r]);
          float p1 = __builtin_amdgcn_exp2f(sf[s][1][r] - mrow[s][r]);
          float p2 = __builtin_amdgcn_exp2f(sf[s][2][r] - mrow[s][r]);
          float p3 = __builtin_amdgcn_exp2f(sf[s][3][r] - mrow[s][r]);
          lrow[s][r] += (p0 + p1) + (p2 + p3);
          uint32_t lo = cvtpk(p0, p1), hi = cvtpk(p2, p3);
          uint32_t* pp = (uint32_t*)(Pc + ((prow * 128 + lr * 8) ^ ((prow & 7) << 4)));
          pp[0] = lo; pp[1] = hi;
        }

      const char* Vc = (const char*)Vb[cur];
      __builtin_amdgcn_s_setprio(1);
#pragma unroll
      for (int st = 0; st < 2; ++st) {
        bf16x8 pf0 = *(const bf16x8*)(Pc + (((lr * 128) + (st * 32 + lk) * 2) ^ kxor));
        bf16x8 pf1 = *(const bf16x8*)(Pc + ((((16 + lr) * 128) + (st * 32 + lk) * 2) ^ kxor));
#pragma unroll
        for (int f = 0; f < 8; ++f) {
          bf16x8 vf = *(const bf16x8*)(Vc + ((((f * 16 + lr) * 128) + (st * 32 + lk) * 2) ^ kxor));
          o[0][f] = __builtin_amdgcn_mfma_f32_16x16x32_bf16(pf0, vf, o[0][f], 0, 0, 0);
          o[1][f] = __builtin_amdgcn_mfma_f32_16x16x32_bf16(pf1, vf, o[1][f], 0, 0, 0);
        }
      }
      __builtin_amdgcn_s_setprio(0);
    }
    __syncthreads();
    cur ^= 1;
  }

#pragma unroll
  for (int s = 0; s < 2; ++s)
#pragma unroll
    for (int r = 0; r < 4; ++r) {
      float l = lrow[s][r];
      l += __shfl_xor(l, 1);
      l += __shfl_xor(l, 2);
      l += __shfl_xor(l, 4);
      l += __shfl_xor(l, 8);
      const float rinv = __builtin_amdgcn_rcpf(l);
      const int row = qw + s * 16 + rbase + r;
#pragma unroll
      for (int f = 0; f < 8; ++f)
        y[((size_t)b * 2048 + row) * 2048 + h * 128 + f * 16 + lr] =
            f2b(o[s][f][r] * rinv);
    }
}

// ---------------- launch ----------------

extern "C" void kernel_launch(void* const* d_in, const int* in_sizes, int n_in,
                              void* d_out, int out_size, void* d_ws, size_t ws_size,
                              hipStream_t stream) {
  const float* x  = (const float*)d_in[0];
  const float* Wq = (const float*)d_in[1];
  const float* bq = (const float*)d_in[2];
  const float* Wk = (const float*)d_in[3];
  const float* bk = (const float*)d_in[4];
  const float* Wv = (const float*)d_in[5];
  const float* bv = (const float*)d_in[6];
  const float* Wo = (const float*)d_in[7];
  const float* bo = (const float*)d_in[8];
  float* out = (float*)d_out;
  char* ws = (char*)d_ws;

  u16* yb  = (u16*)(ws + 0);          // 16 MB (attn output; x-cast buffer deleted)
  u16* Wt  = (u16*)(ws + 16777216);   // 24 MB; front 8 MB reused as Wot, next as vtb
  u16* qb  = (u16*)(ws + 41943040);   // 16 MB
  u16* kb  = (u16*)(ws + 58720256);   // 16 MB
  u16* vb  = (u16*)(ws + 75497472);   // 16 MB (total 88 MB)
  u16* Wot = Wt;                      // [2048][2048] bf16 = 8 MB (written after gemm_qkv)
  u16* vtb = (u16*)(ws + 25165824);   // [B,H,128,T] bf16 = 16 MB

  prep_kernel<<<1536, 256, 0, stream>>>(Wq, Wk, Wv, Wt);
  gemm_qkv_kernel<<<256, 512, 0, stream>>>(x, Wt, qb, kb, vb, bq, bk, bv);
  post_transpose_kernel<<<1536, 256, 0, stream>>>(Wo, Wot, vb, vtb);
  attn_kernel<<<512, 256, 0, stream>>>(qb, kb, vtb, yb);
  gemm_out_kernel<<<256, 512, 0, stream>>>(yb, Wot, out, bo);
}